// Round 12
// baseline (1052.445 us; speedup 1.0000x reference)
//
#include <hip/hip_runtime.h>
#include <cstdint>
#include <math.h>

#define B       64
#define DF      172
#define HDIM    256
#define KSAMP   16
#define THREADS 512

typedef const __attribute__((address_space(1))) unsigned int* gp_t;
typedef __attribute__((address_space(3))) unsigned int* lp_t;

// NOTE: macro params must not collide with float4 member accessors (.x/.y/.z/.w)
#define FMA4(A_, S_, W_) \
  A_.x = fmaf(S_, W_.x, A_.x); A_.y = fmaf(S_, W_.y, A_.y); \
  A_.z = fmaf(S_, W_.z, A_.z); A_.w = fmaf(S_, W_.w, A_.w);

// ---------------- threefry2x32 (bit-exact vs JAX, partitionable scheme) ----------------
__device__ __forceinline__ uint32_t rotl32(uint32_t x, int d) {
  return (x << d) | (x >> (32 - d));
}

__device__ __forceinline__ void threefry2x32(uint32_t k0, uint32_t k1,
                                             uint32_t& x0, uint32_t& x1) {
  const uint32_t ks0 = k0, ks1 = k1, ks2 = k0 ^ k1 ^ 0x1BD11BDAu;
  x0 += ks0; x1 += ks1;
#define TF_R4(ra,rb,rc,rd) \
  x0 += x1; x1 = rotl32(x1, ra); x1 ^= x0; \
  x0 += x1; x1 = rotl32(x1, rb); x1 ^= x0; \
  x0 += x1; x1 = rotl32(x1, rc); x1 ^= x0; \
  x0 += x1; x1 = rotl32(x1, rd); x1 ^= x0;
  TF_R4(13,15,26,6)  x0 += ks1; x1 += ks2 + 1u;
  TF_R4(17,29,16,24) x0 += ks2; x1 += ks0 + 2u;
  TF_R4(13,15,26,6)  x0 += ks0; x1 += ks1 + 3u;
  TF_R4(17,29,16,24) x0 += ks1; x1 += ks2 + 4u;
  TF_R4(13,15,26,6)  x0 += ks2; x1 += ks0 + 5u;
#undef TF_R4
}

// ---------------- wave-private enc GEMM: 1 row x 8 cols per lane, k = 0..171 serial ----------------
// Arow: LDS row (broadcast within 8-lane group); Wp = (float4*)W + cg8*2 (stride 16/k)
__device__ __forceinline__ void enc_wp(const float* __restrict__ Arow,
                                       const float4* __restrict__ Wp,
                                       const float4* __restrict__ bp,
                                       float* __restrict__ outRow, int cg8) {
  float4 lo = bp[0], hi = bp[1];
  float4 w0 = Wp[0], w1 = Wp[1];
  float  a0 = Arow[0];
  for (int k = 0; k < DF; ++k) {
    const float4 wa = w0, wb = w1; const float av = a0;
    if (k < DF - 1) {
      w0 = Wp[(k + 1) * 16]; w1 = Wp[(k + 1) * 16 + 1]; a0 = Arow[k + 1];
    }
    FMA4(lo, av, wa) FMA4(hi, av, wb)
  }
  float4 o0 = make_float4(fmaxf(lo.x, 0.f), fmaxf(lo.y, 0.f), fmaxf(lo.z, 0.f), fmaxf(lo.w, 0.f));
  float4 o1 = make_float4(fmaxf(hi.x, 0.f), fmaxf(hi.y, 0.f), fmaxf(hi.z, 0.f), fmaxf(hi.w, 0.f));
  ((float4*)outRow)[cg8 * 2]     = o0;
  ((float4*)outRow)[cg8 * 2 + 1] = o1;
}

// ---------------- wave-private accum: acc[8 rows][4 h] += enc(own 8 rows) @ Wl[off:off+64]
// Wlp = (float4*)Wl + off*64 + l : lane l covers cols 4l..4l+3 (1 KB/row coalesced/wave)
__device__ __forceinline__ void accum_wp(float4 (&acc)[8],
                                         const float* __restrict__ eb,
                                         const float4* __restrict__ Wlp) {
  float4 w0 = Wlp[0], w1 = Wlp[64], w2 = Wlp[128], w3 = Wlp[192];
  for (int d0 = 0; d0 < 64; d0 += 4) {
    const float4 wa = w0, wb = w1, wc = w2, wd = w3;
    if (d0 < 60) {
      const float4* p = Wlp + (d0 + 4) * 64;
      w0 = p[0]; w1 = p[64]; w2 = p[128]; w3 = p[192];
    }
#pragma unroll
    for (int i = 0; i < 8; ++i) {
      const float4 e = *(const float4*)&eb[i * 64 + d0];  // wave-uniform broadcast
      FMA4(acc[i], e.x, wa) FMA4(acc[i], e.y, wb) FMA4(acc[i], e.z, wc) FMA4(acc[i], e.w, wd)
    }
  }
}

__global__ __launch_bounds__(THREADS, 2)   // VGPR cap 128 (no spill); LDS 67.8KB -> 2 blocks/CU
void AdaptSampler_kernel(const float* __restrict__ rootf,   // [n,172]
                         const float* __restrict__ root_ts, // [n]
                         const float* __restrict__ nf,      // [n,64,172]
                         const float* __restrict__ ef,      // [n,64,172]
                         const float* __restrict__ nts,     // [n,64]
                         const int*   __restrict__ nid,     // [n,64]
                         const float* __restrict__ Wn,      // [172,64]
                         const float* __restrict__ bn,      // [64]
                         const float* __restrict__ We,      // [172,64]
                         const float* __restrict__ be,      // [64]
                         const float* __restrict__ Wl,      // [320,256]
                         const float* __restrict__ Wr,      // [192,256]
                         float* __restrict__ out_probs,     // [n,64]
                         float* __restrict__ out_action)    // [n,16] (as float)
{
  __shared__ float S_lds[B * DF];       // 44032 B: nf -> ef (per-wave 8-row regions)
  __shared__ float encW[B * 64];        // 16384 B: node -> edge -> time -> freq (per-wave rows)
  __shared__ float rootenc[8][192];     // 6144 B: per-wave private copy
  __shared__ float hroot_lds[HDIM];     // 1024 B
  __shared__ float sc_lds[B];           // 256 B
  // total 67840 B -> 2 blocks/CU

  const int n = blockIdx.x;
  const int t = threadIdx.x;
  const int w = t >> 6;        // wave id: owns rows 8w..8w+7
  const int l = t & 63;        // lane
  const int rloc = l >> 3;     // enc: local row
  const int cg8  = l & 7;      // enc: col-group (8 cols)

  float* Sw = S_lds + w * (8 * DF);
  float* ew = encW  + w * (8 * 64);

  // ---- issue nf DMA for own 8 rows (5504 B = 344 float4) ----
  const float* gnf = nf + (size_t)n * B * DF + (size_t)w * 8 * DF;
#pragma unroll
  for (int j = 0; j < 5; ++j)
    __builtin_amdgcn_global_load_lds((gp_t)(gnf + j * 256 + l * 4), (lp_t)(Sw + j * 256), 16, 0, 0);
  if (l < 24)
    __builtin_amdgcn_global_load_lds((gp_t)(gnf + 1280 + l * 4), (lp_t)(Sw + 1280), 16, 0, 0);

  // ---- per-lane invariants (overlap DMA) ----
  const int   nid_l = nid[n * B + l];         // lane l holds row l's nid (all 64)
  const float ts_l  = nts[n * B + l];
  const float rts   = root_ts[n];
  const float w_l   = (float)(1.0 / pow(10.0, 9.0 * (double)l / 63.0));  // np.linspace f64

  // ---- root_feat col l -> wave-private rootenc (identical across waves, bit-exact) ----
  {
    float rf = bn[l];
    const float* rr = rootf + (size_t)n * DF;
#pragma unroll 4
    for (int d = 0; d < DF; ++d) rf = fmaf(rr[d], Wn[d * 64 + l], rf);
    rootenc[w][l]       = fmaxf(rf, 0.0f);
    rootenc[w][64 + l]  = 1.0f;          // cos(0*w)
    rootenc[w][128 + l] = cosf(w_l);     // cos(1*w)
  }

  // ---- node enc (wait own DMA; vmcnt is per-wave) ----
  asm volatile("s_waitcnt vmcnt(0)" ::: "memory");
  __builtin_amdgcn_sched_barrier(0);
  enc_wp(Sw + rloc * DF, (const float4*)Wn + cg8 * 2, (const float4*)bn + cg8 * 2,
         ew + rloc * 64, cg8);

  // ---- issue ef DMA into own (already-consumed) S region ----
  const float* gef = ef + (size_t)n * B * DF + (size_t)w * 8 * DF;
#pragma unroll
  for (int j = 0; j < 5; ++j)
    __builtin_amdgcn_global_load_lds((gp_t)(gef + j * 256 + l * 4), (lp_t)(Sw + j * 256), 16, 0, 0);
  if (l < 24)
    __builtin_amdgcn_global_load_lds((gp_t)(gef + 1280 + l * 4), (lp_t)(Sw + 1280), 16, 0, 0);

  // ---- h_root partial (t-split 2-way, same scheme as passing r9) ----
  {
    const int h = t >> 1, hf = t & 1;
    float a = 0.0f;
    for (int d = hf * 96; d < hf * 96 + 96; ++d)
      a = fmaf(rootenc[w][d], Wr[d * HDIM + h], a);
    a += __shfl_xor(a, 1);
    if (hf == 0) hroot_lds[h] = fmaxf(a, 0.0f);
  }

  // ---- accum node (d 0..63) — covers ef DMA latency ----
  float4 acc[8];
#pragma unroll
  for (int i = 0; i < 8; ++i) acc[i] = make_float4(0.f, 0.f, 0.f, 0.f);
  accum_wp(acc, ew, (const float4*)Wl + l);

  // ---- edge enc (wait own ef DMA) + accum edge (64..127) ----
  asm volatile("s_waitcnt vmcnt(0)" ::: "memory");
  __builtin_amdgcn_sched_barrier(0);
  enc_wp(Sw + rloc * DF, (const float4*)We + cg8 * 2, (const float4*)be + cg8 * 2,
         ew + rloc * 64, cg8);
  accum_wp(acc, ew, (const float4*)Wl + 64 * 64 + l);

  // ---- time cos -> ew (own rows; intra-wave ds ordering) + accum time (128..191) ----
#pragma unroll
  for (int q = 0; q < 8; ++q) {
    const float tsq = __shfl(ts_l, w * 8 + q);
    ew[q * 64 + l] = cosf((rts - tsq) * w_l);
  }
  accum_wp(acc, ew, (const float4*)Wl + 128 * 64 + l);

  // ---- masks (ballot) + freq cos -> ew + accum freq (192..255) ----
  unsigned long long mq[8];
#pragma unroll
  for (int q = 0; q < 8; ++q) {
    const int nr = __shfl(nid_l, w * 8 + q);
    mq[q] = __ballot(nid_l == nr);
    const float fq = (float)__popcll(mq[q]) * 0.015625f;
    ew[q * 64 + l] = cosf(fq * w_l);
  }
  accum_wp(acc, ew, (const float4*)Wl + 192 * 64 + l);

  // ---- iden sparse (256..319): fmaf(0,w,acc)==acc exactly; ascending-d ctz order ----
  {
    const float4* Wli = (const float4*)Wl + 256 * 64 + l;
#pragma unroll
    for (int q = 0; q < 8; ++q) {
      unsigned long long m = mq[q];     // wave-uniform -> no divergence
      while (m) {
        const int d = __builtin_ctzll(m);
        m &= m - 1;
        const float4 wv = Wli[d * 64];
        acc[q].x += wv.x; acc[q].y += wv.y; acc[q].z += wv.z; acc[q].w += wv.w;
      }
    }
  }

  __syncthreads();   // BAR1: hroot_lds ready for all waves

  // ---- scores: relu(h_link) . h_root, butterfly-64 per row ----
  {
    const float4 hrv = ((const float4*)hroot_lds)[l];
#pragma unroll
    for (int q = 0; q < 8; ++q) {
      float s = fmaxf(acc[q].x, 0.f) * hrv.x;
      s = fmaf(fmaxf(acc[q].y, 0.f), hrv.y, s);
      s = fmaf(fmaxf(acc[q].z, 0.f), hrv.z, s);
      s = fmaf(fmaxf(acc[q].w, 0.f), hrv.w, s);
#pragma unroll
      for (int mm = 32; mm >= 1; mm >>= 1) s += __shfl_xor(s, mm);
      if (l == 0) sc_lds[w * 8 + q] = s;
    }
  }
  __syncthreads();   // BAR2: sc_lds ready

  // ---- wave 0: softmax + gumbel + top-16 ----
  if (t < B) {
    float s = sc_lds[t] * 0.0625f;   // / sqrt(256)
    float m = s;
#pragma unroll
    for (int mm = 32; mm >= 1; mm >>= 1) m = fmaxf(m, __shfl_xor(m, mm));
    float e = expf(s - m);
    float sum = e;
#pragma unroll
    for (int mm = 32; mm >= 1; mm >>= 1) sum += __shfl_xor(sum, mm);
    float p = e / sum;
    out_probs[(size_t)n * B + t] = p;

    // partitionable threefry: block input (0, i), draw = out0 ^ out1
    uint32_t i = (uint32_t)(n * B + t);
    uint32_t x0 = 0u, x1 = i;
    threefry2x32(0u, 42u, x0, x1);
    uint32_t bits = x0 ^ x1;
    float f = __uint_as_float((bits >> 9) | 0x3f800000u) - 1.0f;
    const float TINY = 1.1754943508222875e-38f;
    float u = fmaxf(f * (1.0f - TINY) + TINY, TINY);
    float g = -logf(-logf(u));
    float keyv = logf(p + 1e-20f) + g;

    float v = keyv;
    for (int k = 0; k < KSAMP; ++k) {
      float bv = v; int bi = t;
#pragma unroll
      for (int mm = 32; mm >= 1; mm >>= 1) {
        float ov = __shfl_xor(bv, mm);
        int   oi = __shfl_xor(bi, mm);
        if (ov > bv || (ov == bv && oi < bi)) { bv = ov; bi = oi; }
      }
      if (t == 0) out_action[(size_t)n * KSAMP + k] = (float)bi;
      if (t == bi) v = -3.402823466e+38f;
    }
  }
}

extern "C" void kernel_launch(void* const* d_in, const int* in_sizes, int n_in,
                              void* d_out, int out_size, void* d_ws, size_t ws_size,
                              hipStream_t stream) {
  const float* rootf = (const float*)d_in[0];
  const float* rts   = (const float*)d_in[1];
  const float* nf    = (const float*)d_in[2];
  const float* ef    = (const float*)d_in[3];
  const float* nts   = (const float*)d_in[4];
  const int*   nid   = (const int*)d_in[5];
  const float* Wn    = (const float*)d_in[6];
  const float* bn    = (const float*)d_in[7];
  const float* We    = (const float*)d_in[8];
  const float* be    = (const float*)d_in[9];
  const float* Wl    = (const float*)d_in[10];
  const float* Wr    = (const float*)d_in[11];

  const int n = in_sizes[1];                   // 4096 rows
  float* probs  = (float*)d_out;               // [n,64] f32
  float* action = probs + (size_t)n * B;       // [n,16] written as f32 values

  AdaptSampler_kernel<<<dim3(n), dim3(THREADS), 0, stream>>>(
      rootf, rts, nf, ef, nts, nid, Wn, bn, We, be, Wl, Wr, probs, action);
}